// Round 1
// baseline (675.704 us; speedup 1.0000x reference)
//
#include <hip/hip_runtime.h>
#include <math.h>

#define BMT 64
#define BNT 64
#define BKT 16
#define PADT 4

enum { M_NONE = 0, M_BIAS = 1, M_BIAS_RELU = 2, M_BIAS_MUL = 3, M_DIST = 4 };

// C[M,N] = epilogue( A[M,K] @ opB + bias )
// B_WEIGHT=true : B is [N,K] row-major (torch Linear weight), dot along contiguous K
// B_WEIGHT=false: B is [K,N] row-major
template<int MODE, bool B_WEIGHT>
__global__ __launch_bounds__(256)
void gemm_kernel(int M, int N, int K,
                 const float* __restrict__ A, int lda, long sAb,
                 const float* __restrict__ B, int ldb, long sBb,
                 float* __restrict__ C, int ldc, long sCb,
                 const float* __restrict__ bias,
                 const float* __restrict__ Xmul, long sXb)
{
    __shared__ float As[BKT][BMT + PADT];
    __shared__ float Bs[BKT][BNT + PADT];

    int bz = blockIdx.z;
    A += (long)bz * sAb;
    B += (long)bz * sBb;
    C += (long)bz * sCb;
    const float* X = (MODE == M_BIAS_MUL) ? (Xmul + (long)bz * sXb) : nullptr;

    int m0 = blockIdx.y * BMT;
    int n0 = blockIdx.x * BNT;
    int tid = threadIdx.x;
    int tx = tid & 15;   // output col group
    int ty = tid >> 4;   // output row group

    // load indices (transpose-into-LDS path)
    int lc = tid & 15;   // k within tile
    int lr = tid >> 4;   // row base, rows lr + i*16
    // load indices (direct path, B=[K,N])
    int bn_n = tid & 63;
    int bn_k = tid >> 6; // k = bn_k + i*4

    float acc[4][4] = {};

    for (int k0 = 0; k0 < K; k0 += BKT) {
        #pragma unroll
        for (int i = 0; i < 4; ++i) {
            int r = lr + i * 16;
            As[lc][r] = A[(long)(m0 + r) * lda + (k0 + lc)];
        }
        if (B_WEIGHT) {
            #pragma unroll
            for (int i = 0; i < 4; ++i) {
                int r = lr + i * 16;
                Bs[lc][r] = B[(long)(n0 + r) * ldb + (k0 + lc)];
            }
        } else {
            #pragma unroll
            for (int i = 0; i < 4; ++i) {
                int kk = bn_k + i * 4;
                Bs[kk][bn_n] = B[(long)(k0 + kk) * ldb + (n0 + bn_n)];
            }
        }
        __syncthreads();

        #pragma unroll
        for (int k = 0; k < BKT; ++k) {
            float a[4], bb[4];
            #pragma unroll
            for (int i = 0; i < 4; ++i) a[i] = As[k][ty * 4 + i];
            #pragma unroll
            for (int j = 0; j < 4; ++j) bb[j] = Bs[k][tx * 4 + j];
            #pragma unroll
            for (int i = 0; i < 4; ++i)
                #pragma unroll
                for (int j = 0; j < 4; ++j)
                    acc[i][j] += a[i] * bb[j];
        }
        __syncthreads();
    }

    #pragma unroll
    for (int i = 0; i < 4; ++i) {
        int m = m0 + ty * 4 + i;
        #pragma unroll
        for (int j = 0; j < 4; ++j) {
            int n = n0 + tx * 4 + j;
            float v = acc[i][j];
            if (MODE == M_BIAS || MODE == M_BIAS_RELU || MODE == M_BIAS_MUL) v += bias[n];
            if (MODE == M_BIAS_RELU) v = fmaxf(v, 0.0f);
            if (MODE == M_BIAS_MUL) v *= X[(long)m * ldc + n];
            if (MODE == M_DIST) v = -(v * v) * (0.5f / 512.0f);
            C[(long)m * ldc + n] = v;
        }
    }
}

// row softmax over 2048 contiguous floats, one block (256 thr) per row
__global__ __launch_bounds__(256)
void softmax2048(float* __restrict__ S)
{
    long row = blockIdx.x;
    float4* p = (float4*)(S + row * 2048);
    int tid = threadIdx.x;
    int lane = tid & 63, w = tid >> 6;

    float4 a = p[tid];
    float4 b = p[tid + 256];

    float m = fmaxf(fmaxf(fmaxf(a.x, a.y), fmaxf(a.z, a.w)),
                    fmaxf(fmaxf(b.x, b.y), fmaxf(b.z, b.w)));
    #pragma unroll
    for (int o = 32; o; o >>= 1) m = fmaxf(m, __shfl_xor(m, o));

    __shared__ float redm[4];
    __shared__ float reds[4];
    if (lane == 0) redm[w] = m;
    __syncthreads();
    m = fmaxf(fmaxf(redm[0], redm[1]), fmaxf(redm[2], redm[3]));

    a.x = expf(a.x - m); a.y = expf(a.y - m); a.z = expf(a.z - m); a.w = expf(a.w - m);
    b.x = expf(b.x - m); b.y = expf(b.y - m); b.z = expf(b.z - m); b.w = expf(b.w - m);

    float s = a.x + a.y + a.z + a.w + b.x + b.y + b.z + b.w;
    #pragma unroll
    for (int o = 32; o; o >>= 1) s += __shfl_xor(s, o);
    if (lane == 0) reds[w] = s;
    __syncthreads();
    s = reds[0] + reds[1] + reds[2] + reds[3];

    float inv = 1.0f / s;
    a.x *= inv; a.y *= inv; a.z *= inv; a.w *= inv;
    b.x *= inv; b.y *= inv; b.z *= inv; b.w *= inv;
    p[tid] = a;
    p[tid + 256] = b;
}

extern "C" void kernel_launch(void* const* d_in, const int* in_sizes, int n_in,
                              void* d_out, int out_size, void* d_ws, size_t ws_size,
                              hipStream_t stream)
{
    const float* KEY   = (const float*)d_in[0];
    const float* VALUE = (const float*)d_in[1];
    const float* QUERY = (const float*)d_in[2];
    const float* W1w = (const float*)d_in[3];
    const float* W1b = (const float*)d_in[4];
    const float* W2w = (const float*)d_in[5];
    const float* W2b = (const float*)d_in[6];
    const float* W3w = (const float*)d_in[7];
    const float* W3b = (const float*)d_in[8];
    const float* V1w = (const float*)d_in[9];
    const float* V1b = (const float*)d_in[10];
    const float* V2w = (const float*)d_in[11];
    const float* V2b = (const float*)d_in[12];
    const float* V3w = (const float*)d_in[13];
    const float* V3b = (const float*)d_in[14];
    const float* Wow = (const float*)d_in[15];
    const float* Wob = (const float*)d_in[16];
    float* out = (float*)d_out;

    const int Bb = 2, N = 2048, Mq = 2048, DK = 512, H = 512;
    const long R = (long)Bb * N;  // 4096 rows for flattened [B*N, *] ops

    float* ws = (float*)d_ws;
    float* h1  = ws;                       // [4096,512]
    float* h2  = h1 + R * H;               // [4096,512]
    float* ks  = h2 + R * H;               // KEY_s  [B,N,DK]
    float* qs  = ks + R * DK;              // QUERY_s[B,M,DK]
    float* vs  = qs + R * DK;              // VALUE_s[B,N,H]
    float* sT  = vs + R * H;               // [B,M,N] scores (query-major)
    float* ctx = sT + (long)Bb * Mq * N;   // [B,M,H]

    dim3 blk(256);

    auto g512 = [&](const float* A, const float* W, const float* bvec, float* C,
                    const float* X, int mode) {
        dim3 grid(512 / BNT, 4096 / BMT, 1);
        switch (mode) {
        case M_BIAS_RELU:
            gemm_kernel<M_BIAS_RELU, true><<<grid, blk, 0, stream>>>(
                4096, 512, 512, A, 512, 0, W, 512, 0, C, 512, 0, bvec, nullptr, 0);
            break;
        case M_BIAS_MUL:
            gemm_kernel<M_BIAS_MUL, true><<<grid, blk, 0, stream>>>(
                4096, 512, 512, A, 512, 0, W, 512, 0, C, 512, 0, bvec, X, 0);
            break;
        case M_BIAS:
            gemm_kernel<M_BIAS, true><<<grid, blk, 0, stream>>>(
                4096, 512, 512, A, 512, 0, W, 512, 0, C, 512, 0, bvec, nullptr, 0);
            break;
        }
    };

    // --- K/Q MLP (shared weights) ---
    g512(KEY, W1w, W1b, h1, nullptr, M_BIAS_RELU);
    g512(h1,  W2w, W2b, h2, nullptr, M_BIAS_RELU);
    g512(h2,  W3w, W3b, ks, KEY,     M_BIAS_MUL);

    g512(QUERY, W1w, W1b, h1, nullptr, M_BIAS_RELU);
    g512(h1,    W2w, W2b, h2, nullptr, M_BIAS_RELU);
    g512(h2,    W3w, W3b, qs, QUERY,   M_BIAS_MUL);

    // --- V MLP ---
    g512(VALUE, V1w, V1b, h1, nullptr, M_BIAS_RELU);
    g512(h1,    V2w, V2b, h2, nullptr, M_BIAS_RELU);
    g512(h2,    V3w, V3b, vs, VALUE,   M_BIAS_MUL);

    // --- scores: sT[b,q,i] = -0.5*(dot(qs[q],ks[i])/sqrt(512))^2 ---
    {
        dim3 grid(N / BNT, Mq / BMT, Bb);
        gemm_kernel<M_DIST, true><<<grid, blk, 0, stream>>>(
            Mq, N, DK,
            qs, DK, (long)Mq * DK,
            ks, DK, (long)N * DK,
            sT, N, (long)Mq * N,
            nullptr, nullptr, 0);
    }

    // --- softmax over keys (contiguous rows of sT) ---
    softmax2048<<<dim3(Bb * Mq), blk, 0, stream>>>(sT);

    // --- context: ctx[b,q,j] = sum_i sT[b,q,i] * vs[b,i,j] ---
    {
        dim3 grid(H / BNT, Mq / BMT, Bb);
        gemm_kernel<M_NONE, false><<<grid, blk, 0, stream>>>(
            Mq, H, N,
            sT, N, (long)Mq * N,
            vs, H, (long)N * H,
            ctx, H, (long)Mq * H,
            nullptr, nullptr, 0);
    }

    // --- output projection ---
    g512(ctx, Wow, Wob, out, nullptr, M_BIAS);
}

// Round 3
// 367.555 us; speedup vs baseline: 1.8384x; 1.8384x over previous
//
#include <hip/hip_runtime.h>
#include <math.h>

typedef unsigned short u16;
typedef unsigned int u32;
typedef __attribute__((ext_vector_type(8))) short short8;
typedef __attribute__((ext_vector_type(4))) float f32x4;
typedef __attribute__((ext_vector_type(4))) u16 u16x4;

__device__ __forceinline__ void gload16(const void* g, void* l) {
    __builtin_amdgcn_global_load_lds(
        (__attribute__((address_space(1))) u32*)g,
        (__attribute__((address_space(3))) u32*)l, 16, 0, 0);
}

__device__ __forceinline__ u16 f2bf_rne(float v) {
    u32 u = __builtin_bit_cast(u32, v);
    return (u16)((u + 0x7FFFu + ((u >> 16) & 1u)) >> 16);
}
__device__ __forceinline__ float bf2f(u16 h) {
    u32 u = ((u32)h) << 16;
    return __builtin_bit_cast(float, u);
}
__device__ __forceinline__ void splt(float v, u16& h, u16& l) {
    h = f2bf_rne(v);
    l = f2bf_rne(v - bf2f(h));
}

enum { EP_RELU_SPLIT, EP_MUL_SPLIT, EP_MUL_F32, EP_DIST_F32, EP_SPLIT, EP_BIAS_F32 };

// C[M,N] = epilogue(A[M,K] @ B[N,K]^T), A/B as (hi,lo) bf16 pairs, 3-product split GEMM.
template<int BM, int BN, int EP>
__global__ __launch_bounds__(256)
void gemm_split(int M, int N, int K,
                const u16* __restrict__ Ah, const u16* __restrict__ Al, int lda, long sA,
                const u16* __restrict__ Bh, const u16* __restrict__ Bl, int ldb, long sB,
                float* __restrict__ Cf, u16* __restrict__ Ch, u16* __restrict__ Cl,
                int ldc, long sC,
                const float* __restrict__ bias,
                const float* __restrict__ X)
{
    constexpr int SUBM = BM / 2, SUBN = BN / 2;
    constexpr int MR = SUBM / 16, NR = SUBN / 16;
    __shared__ u16 LA_h[BM * 32];
    __shared__ u16 LA_l[BM * 32];
    __shared__ u16 LB_h[BN * 32];
    __shared__ u16 LB_l[BN * 32];

    const int tid = threadIdx.x;
    const int lane = tid & 63;
    const int wave = tid >> 6;
    const int wr = wave >> 1, wc = wave & 1;
    const int fr = lane & 15, kg = lane >> 4;

    const int bz = blockIdx.z;
    Ah += bz * sA; Al += bz * sA;
    Bh += bz * sB; Bl += bz * sB;
    const long cb = (long)bz * sC;

    const int m0 = blockIdx.y * BM, n0 = blockIdx.x * BN;

    f32x4 acc[MR][NR];
    #pragma unroll
    for (int i = 0; i < MR; ++i)
        #pragma unroll
        for (int j = 0; j < NR; ++j)
            acc[i][j] = (f32x4){0.f, 0.f, 0.f, 0.f};

    for (int k0 = 0; k0 < K; k0 += 32) {
        #pragma unroll
        for (int c0 = 0; c0 < BM * 4; c0 += 256) {
            int c = c0 + tid;
            long so = (long)(m0 + (c >> 2)) * lda + k0 + (c & 3) * 8;
            gload16(Ah + so, &LA_h[c * 8]);
            gload16(Al + so, &LA_l[c * 8]);
        }
        #pragma unroll
        for (int c0 = 0; c0 < BN * 4; c0 += 256) {
            int c = c0 + tid;
            long so = (long)(n0 + (c >> 2)) * ldb + k0 + (c & 3) * 8;
            gload16(Bh + so, &LB_h[c * 8]);
            gload16(Bl + so, &LB_l[c * 8]);
        }
        __syncthreads();

        short8 ah[MR], al[MR], bh[NR], bl[NR];
        #pragma unroll
        for (int i = 0; i < MR; ++i) {
            int off = (wr * SUBM + i * 16 + fr) * 32 + kg * 8;
            ah[i] = *(const short8*)&LA_h[off];
            al[i] = *(const short8*)&LA_l[off];
        }
        #pragma unroll
        for (int j = 0; j < NR; ++j) {
            int off = (wc * SUBN + j * 16 + fr) * 32 + kg * 8;
            bh[j] = *(const short8*)&LB_h[off];
            bl[j] = *(const short8*)&LB_l[off];
        }
        #pragma unroll
        for (int i = 0; i < MR; ++i)
            #pragma unroll
            for (int j = 0; j < NR; ++j) {
                acc[i][j] = __builtin_amdgcn_mfma_f32_16x16x32_bf16(ah[i], bh[j], acc[i][j], 0, 0, 0);
                acc[i][j] = __builtin_amdgcn_mfma_f32_16x16x32_bf16(ah[i], bl[j], acc[i][j], 0, 0, 0);
                acc[i][j] = __builtin_amdgcn_mfma_f32_16x16x32_bf16(al[i], bh[j], acc[i][j], 0, 0, 0);
            }
        __syncthreads();
    }

    #pragma unroll
    for (int i = 0; i < MR; ++i)
        #pragma unroll
        for (int j = 0; j < NR; ++j)
            #pragma unroll
            for (int r = 0; r < 4; ++r) {
                int row = m0 + wr * SUBM + i * 16 + kg * 4 + r;
                int col = n0 + wc * SUBN + j * 16 + fr;
                float v = acc[i][j][r];
                long o = cb + (long)row * ldc + col;
                if constexpr (EP == EP_RELU_SPLIT) {
                    v += bias[col]; v = fmaxf(v, 0.f);
                    u16 h, l; splt(v, h, l); Ch[o] = h; Cl[o] = l;
                } else if constexpr (EP == EP_MUL_SPLIT) {
                    v += bias[col]; v *= X[(long)row * ldc + col];
                    u16 h, l; splt(v, h, l); Ch[o] = h; Cl[o] = l;
                } else if constexpr (EP == EP_MUL_F32) {
                    v += bias[col]; v *= X[(long)row * ldc + col];
                    Cf[o] = v;
                } else if constexpr (EP == EP_DIST_F32) {
                    Cf[o] = -(v * v) * (1.0f / 1024.0f);
                } else if constexpr (EP == EP_SPLIT) {
                    u16 h, l; splt(v, h, l); Ch[o] = h; Cl[o] = l;
                } else {
                    Cf[o] = v + bias[col];
                }
            }
}

// softmax over 2048 contiguous floats per row; writes hi/lo bf16 in place
// (row r bytes: [0,4K) = 2048 hi shorts, [4K,8K) = 2048 lo shorts)
__global__ __launch_bounds__(256)
void softmax_split(float* __restrict__ S)
{
    long row = blockIdx.x;
    float* base = S + row * 2048;
    int tid = threadIdx.x;
    int lane = tid & 63, w = tid >> 6;

    float4 a = ((float4*)base)[tid];
    float4 b = ((float4*)base)[tid + 256];

    float m = fmaxf(fmaxf(fmaxf(a.x, a.y), fmaxf(a.z, a.w)),
                    fmaxf(fmaxf(b.x, b.y), fmaxf(b.z, b.w)));
    #pragma unroll
    for (int o = 32; o; o >>= 1) m = fmaxf(m, __shfl_xor(m, o));

    __shared__ float redm[4];
    __shared__ float reds[4];
    if (lane == 0) redm[w] = m;
    __syncthreads();
    m = fmaxf(fmaxf(redm[0], redm[1]), fmaxf(redm[2], redm[3]));

    a.x = expf(a.x - m); a.y = expf(a.y - m); a.z = expf(a.z - m); a.w = expf(a.w - m);
    b.x = expf(b.x - m); b.y = expf(b.y - m); b.z = expf(b.z - m); b.w = expf(b.w - m);

    float s = a.x + a.y + a.z + a.w + b.x + b.y + b.z + b.w;
    #pragma unroll
    for (int o = 32; o; o >>= 1) s += __shfl_xor(s, o);
    if (lane == 0) reds[w] = s;
    __syncthreads();
    s = reds[0] + reds[1] + reds[2] + reds[3];

    float inv = 1.0f / s;
    u16* hb = (u16*)base;
    u16* lb = hb + 2048;
    u16x4 h4, l4;
    {
        u16 h, l;
        splt(a.x * inv, h, l); h4.x = h; l4.x = l;
        splt(a.y * inv, h, l); h4.y = h; l4.y = l;
        splt(a.z * inv, h, l); h4.z = h; l4.z = l;
        splt(a.w * inv, h, l); h4.w = h; l4.w = l;
    }
    ((u16x4*)hb)[tid] = h4;
    ((u16x4*)lb)[tid] = l4;
    {
        u16 h, l;
        splt(b.x * inv, h, l); h4.x = h; l4.x = l;
        splt(b.y * inv, h, l); h4.y = h; l4.y = l;
        splt(b.z * inv, h, l); h4.z = h; l4.z = l;
        splt(b.w * inv, h, l); h4.w = h; l4.w = l;
    }
    ((u16x4*)hb)[tid + 256] = h4;
    ((u16x4*)lb)[tid + 256] = l4;
}

// vs f32 [b][2048][512] -> vsT hi/lo bf16 [b][512][2048]
__global__ __launch_bounds__(256)
void transpose_split(const float* __restrict__ vs, u16* __restrict__ tH, u16* __restrict__ tL)
{
    __shared__ float t[32][33];
    int b = blockIdx.z;
    const float* src = vs + (long)b * 2048 * 512;
    u16* th = tH + (long)b * 512 * 2048;
    u16* tl = tL + (long)b * 512 * 2048;
    int c0 = blockIdx.x * 32;
    int r0 = blockIdx.y * 32;
    int tx = threadIdx.x, ty = threadIdx.y;
    #pragma unroll
    for (int k = 0; k < 4; ++k)
        t[ty + 8 * k][tx] = src[(long)(r0 + ty + 8 * k) * 512 + c0 + tx];
    __syncthreads();
    #pragma unroll
    for (int k = 0; k < 4; ++k) {
        float v = t[tx][ty + 8 * k];
        u16 h, l; splt(v, h, l);
        long o = (long)(c0 + ty + 8 * k) * 2048 + r0 + tx;
        th[o] = h; tl[o] = l;
    }
}

__global__ __launch_bounds__(256)
void split_arr(const float* __restrict__ in, u16* __restrict__ hi, u16* __restrict__ lo, int n4)
{
    int i = blockIdx.x * 256 + threadIdx.x;
    if (i >= n4) return;
    float4 v = ((const float4*)in)[i];
    u16x4 h4, l4;
    u16 h, l;
    splt(v.x, h, l); h4.x = h; l4.x = l;
    splt(v.y, h, l); h4.y = h; l4.y = l;
    splt(v.z, h, l); h4.z = h; l4.z = l;
    splt(v.w, h, l); h4.w = h; l4.w = l;
    ((u16x4*)hi)[i] = h4;
    ((u16x4*)lo)[i] = l4;
}

extern "C" void kernel_launch(void* const* d_in, const int* in_sizes, int n_in,
                              void* d_out, int out_size, void* d_ws, size_t ws_size,
                              hipStream_t stream)
{
    const float* KEY   = (const float*)d_in[0];
    const float* VALUE = (const float*)d_in[1];
    const float* QUERY = (const float*)d_in[2];
    const float* Wp[7] = {(const float*)d_in[3], (const float*)d_in[5], (const float*)d_in[7],
                          (const float*)d_in[9], (const float*)d_in[11], (const float*)d_in[13],
                          (const float*)d_in[15]};
    const float* W1b = (const float*)d_in[4];
    const float* W2b = (const float*)d_in[6];
    const float* W3b = (const float*)d_in[8];
    const float* V1b = (const float*)d_in[10];
    const float* V2b = (const float*)d_in[12];
    const float* V3b = (const float*)d_in[14];
    const float* Wob = (const float*)d_in[16];
    float* out = (float*)d_out;

    const long RH = 4096L * 512;   // elements of a [4096,512] matrix

    u16* inH = (u16*)d_ws;
    u16* inL = inH + RH;
    u16* p = inL + RH;
    u16 *wH[7], *wL[7];
    for (int i = 0; i < 7; ++i) { wH[i] = p; p += 512 * 512; wL[i] = p; p += 512 * 512; }
    u16* h1H = p;  u16* h1L = h1H + RH;  p = h1L + RH;
    u16* h2H = p;  u16* h2L = h2H + RH;  p = h2L + RH;
    u16* ksH = p;  u16* ksL = ksH + RH;  p = ksL + RH;
    u16* qsH = p;  u16* qsL = qsH + RH;  p = qsL + RH;
    float* sT = (float*)p;               // [2][2048][2048] f32 -> becomes hi/lo after softmax
    // aliases (lifetime-disjoint reuse)
    float* vs = (float*)inH;             // VALUE_s f32 (input split region, free by then)
    u16* vtH = h1H; u16* vtL = h1L;      // vsT hi/lo into h1 region
    u16* ctH = h2H; u16* ctL = h2L;      // ctx hi/lo into h2 region

    dim3 blk(256);

    // split weights + KEY
    for (int i = 0; i < 7; ++i)
        split_arr<<<256, blk, 0, stream>>>(Wp[i], wH[i], wL[i], 512 * 512 / 4);
    split_arr<<<2048, blk, 0, stream>>>(KEY, inH, inL, (int)(RH / 4));

    dim3 gMLP(512 / 64, 4096 / 128, 1);

    // K-path MLP
    gemm_split<128, 64, EP_RELU_SPLIT><<<gMLP, blk, 0, stream>>>(
        4096, 512, 512, inH, inL, 512, 0, wH[0], wL[0], 512, 0,
        nullptr, h1H, h1L, 512, 0, W1b, nullptr);
    gemm_split<128, 64, EP_RELU_SPLIT><<<gMLP, blk, 0, stream>>>(
        4096, 512, 512, h1H, h1L, 512, 0, wH[1], wL[1], 512, 0,
        nullptr, h2H, h2L, 512, 0, W2b, nullptr);
    gemm_split<128, 64, EP_MUL_SPLIT><<<gMLP, blk, 0, stream>>>(
        4096, 512, 512, h2H, h2L, 512, 0, wH[2], wL[2], 512, 0,
        nullptr, ksH, ksL, 512, 0, W3b, KEY);

    // Q-path MLP
    split_arr<<<2048, blk, 0, stream>>>(QUERY, inH, inL, (int)(RH / 4));
    gemm_split<128, 64, EP_RELU_SPLIT><<<gMLP, blk, 0, stream>>>(
        4096, 512, 512, inH, inL, 512, 0, wH[0], wL[0], 512, 0,
        nullptr, h1H, h1L, 512, 0, W1b, nullptr);
    gemm_split<128, 64, EP_RELU_SPLIT><<<gMLP, blk, 0, stream>>>(
        4096, 512, 512, h1H, h1L, 512, 0, wH[1], wL[1], 512, 0,
        nullptr, h2H, h2L, 512, 0, W2b, nullptr);
    gemm_split<128, 64, EP_MUL_SPLIT><<<gMLP, blk, 0, stream>>>(
        4096, 512, 512, h2H, h2L, 512, 0, wH[2], wL[2], 512, 0,
        nullptr, qsH, qsL, 512, 0, W3b, QUERY);

    // V-path MLP
    split_arr<<<2048, blk, 0, stream>>>(VALUE, inH, inL, (int)(RH / 4));
    gemm_split<128, 64, EP_RELU_SPLIT><<<gMLP, blk, 0, stream>>>(
        4096, 512, 512, inH, inL, 512, 0, wH[3], wL[3], 512, 0,
        nullptr, h1H, h1L, 512, 0, V1b, nullptr);
    gemm_split<128, 64, EP_RELU_SPLIT><<<gMLP, blk, 0, stream>>>(
        4096, 512, 512, h1H, h1L, 512, 0, wH[4], wL[4], 512, 0,
        nullptr, h2H, h2L, 512, 0, V2b, nullptr);
    gemm_split<128, 64, EP_MUL_F32><<<gMLP, blk, 0, stream>>>(
        4096, 512, 512, h2H, h2L, 512, 0, wH[5], wL[5], 512, 0,
        vs, nullptr, nullptr, 512, 0, V3b, VALUE);

    // vs -> vsT hi/lo
    transpose_split<<<dim3(16, 64, 2), dim3(32, 8), 0, stream>>>(vs, vtH, vtL);

    // dist: sT[b,q,key] = -(qs.ks/sqrt(512))^2/2
    gemm_split<128, 128, EP_DIST_F32><<<dim3(16, 16, 2), blk, 0, stream>>>(
        2048, 2048, 512,
        qsH, qsL, 512, 2048L * 512,
        ksH, ksL, 512, 2048L * 512,
        sT, nullptr, nullptr, 2048, 2048L * 2048, nullptr, nullptr);

    // softmax over keys, emits hi/lo bf16 in place
    softmax_split<<<dim3(2 * 2048), blk, 0, stream>>>(sT);

    // context: ctx[b,q,j] = sum_key w[q,key] * vsT[j,key]
    gemm_split<128, 64, EP_SPLIT><<<dim3(8, 16, 2), blk, 0, stream>>>(
        2048, 512, 2048,
        (u16*)sT, (u16*)sT + 2048, 4096, 2048L * 4096,
        vtH, vtL, 2048, 512L * 2048,
        nullptr, ctH, ctL, 512, 2048L * 512, nullptr, nullptr);

    // output projection
    gemm_split<128, 64, EP_BIAS_F32><<<dim3(8, 32, 1), blk, 0, stream>>>(
        4096, 512, 512, ctH, ctL, 512, 0, wH[6], wL[6], 512, 0,
        out, nullptr, nullptr, 512, 0, Wob, nullptr);
}

// Round 4
// 305.935 us; speedup vs baseline: 2.2087x; 1.2014x over previous
//
#include <hip/hip_runtime.h>
#include <math.h>

typedef unsigned short u16;
typedef unsigned int u32;
typedef __attribute__((ext_vector_type(8))) short short8;
typedef __attribute__((ext_vector_type(4))) float f32x4;
typedef __attribute__((ext_vector_type(4))) u16 u16x4;

__device__ __forceinline__ void gload16(const void* g, void* l) {
    __builtin_amdgcn_global_load_lds(
        (__attribute__((address_space(1))) u32*)g,
        (__attribute__((address_space(3))) u32*)l, 16, 0, 0);
}

__device__ __forceinline__ u16 f2bf_rne(float v) {
    u32 u = __builtin_bit_cast(u32, v);
    return (u16)((u + 0x7FFFu + ((u >> 16) & 1u)) >> 16);
}
__device__ __forceinline__ float bf2f(u16 h) {
    u32 u = ((u32)h) << 16;
    return __builtin_bit_cast(float, u);
}
__device__ __forceinline__ void splt(float v, u16& h, u16& l) {
    h = f2bf_rne(v);
    l = f2bf_rne(v - bf2f(h));
}

enum { EP_RELU, EP_MUL };          // gemm_mlp epilogues
enum { EP_DIST16, EP_PART, EP_BIASF }; // gemm_split epilogues

// ---------------- merged 3-section MLP GEMM: [12288,512] x [512,512]^T ----------------
// sections of 4096 rows: 0=KEY,1=QUERY (shared W), 2=VALUE (V weights)
template<int EP>
__global__ __launch_bounds__(256)
void gemm_mlp(const u16* __restrict__ Ah, const u16* __restrict__ Al,
              const u16* __restrict__ BHkq, const u16* __restrict__ BLkq,
              const u16* __restrict__ BHv, const u16* __restrict__ BLv,
              const float* __restrict__ bias_kq, const float* __restrict__ bias_v,
              const float* __restrict__ Xk, const float* __restrict__ Xq,
              const float* __restrict__ Xv,
              u16* __restrict__ Ch, u16* __restrict__ Cl)
{
    constexpr int BM = 128, BN = 64;
    constexpr int MR = 4, NR = 2;   // per-wave 64x32 (waves 2x2)
    __shared__ u16 LA_h[BM * 32];
    __shared__ u16 LA_l[BM * 32];
    __shared__ u16 LB_h[BN * 32];
    __shared__ u16 LB_l[BN * 32];

    const int tid = threadIdx.x;
    const int lane = tid & 63;
    const int wave = tid >> 6;
    const int wr = wave >> 1, wc = wave & 1;
    const int fr = lane & 15, kg = lane >> 4;

    const int m0 = blockIdx.y * BM, n0 = blockIdx.x * BN;
    const int sec = blockIdx.y >> 5;          // 0,1,2
    const u16* Bh = (sec == 2) ? BHv : BHkq;
    const u16* Bl = (sec == 2) ? BLv : BLkq;
    const float* bias = (sec == 2) ? bias_v : bias_kq;

    f32x4 acc[MR][NR];
    #pragma unroll
    for (int i = 0; i < MR; ++i)
        #pragma unroll
        for (int j = 0; j < NR; ++j)
            acc[i][j] = (f32x4){0.f, 0.f, 0.f, 0.f};

    for (int k0 = 0; k0 < 512; k0 += 32) {
        #pragma unroll
        for (int c0 = 0; c0 < BM * 4; c0 += 256) {
            int c = c0 + tid;
            long so = (long)(m0 + (c >> 2)) * 512 + k0 + (c & 3) * 8;
            gload16(Ah + so, &LA_h[c * 8]);
            gload16(Al + so, &LA_l[c * 8]);
        }
        {
            int c = tid;
            long so = (long)(n0 + (c >> 2)) * 512 + k0 + (c & 3) * 8;
            gload16(Bh + so, &LB_h[c * 8]);
            gload16(Bl + so, &LB_l[c * 8]);
        }
        __syncthreads();

        short8 ah[MR], al[MR], bh[NR], bl[NR];
        #pragma unroll
        for (int i = 0; i < MR; ++i) {
            int off = (wr * 64 + i * 16 + fr) * 32 + kg * 8;
            ah[i] = *(const short8*)&LA_h[off];
            al[i] = *(const short8*)&LA_l[off];
        }
        #pragma unroll
        for (int j = 0; j < NR; ++j) {
            int off = (wc * 32 + j * 16 + fr) * 32 + kg * 8;
            bh[j] = *(const short8*)&LB_h[off];
            bl[j] = *(const short8*)&LB_l[off];
        }
        #pragma unroll
        for (int i = 0; i < MR; ++i)
            #pragma unroll
            for (int j = 0; j < NR; ++j) {
                acc[i][j] = __builtin_amdgcn_mfma_f32_16x16x32_bf16(ah[i], bh[j], acc[i][j], 0, 0, 0);
                acc[i][j] = __builtin_amdgcn_mfma_f32_16x16x32_bf16(ah[i], bl[j], acc[i][j], 0, 0, 0);
                acc[i][j] = __builtin_amdgcn_mfma_f32_16x16x32_bf16(al[i], bh[j], acc[i][j], 0, 0, 0);
            }
        __syncthreads();
    }

    const float* X = (EP == EP_MUL) ? ((sec == 0) ? Xk : (sec == 1) ? Xq : Xv) : nullptr;

    #pragma unroll
    for (int i = 0; i < MR; ++i)
        #pragma unroll
        for (int j = 0; j < NR; ++j)
            #pragma unroll
            for (int r = 0; r < 4; ++r) {
                int row = m0 + wr * 64 + i * 16 + kg * 4 + r;
                int col = n0 + wc * 32 + j * 16 + fr;
                float v = acc[i][j][r] + bias[col];
                if constexpr (EP == EP_RELU) {
                    v = fmaxf(v, 0.f);
                } else {
                    v *= X[(long)(row - (sec << 12)) * 512 + col];
                }
                long o = (long)row * 512 + col;
                u16 h, l; splt(v, h, l);
                Ch[o] = h; Cl[o] = l;
            }
}

// ---------------- generic split GEMM: C = epi(A[M,K] @ B[N,K]^T) ----------------
template<int BM, int BN, int EP>
__global__ __launch_bounds__(256)
void gemm_split(int M, int N, int K,
                const u16* __restrict__ Ah, const u16* __restrict__ Al, int lda, long sA,
                const u16* __restrict__ Bh, const u16* __restrict__ Bl, int ldb, long sB,
                float* __restrict__ Cf, u16* __restrict__ Ch, u16* __restrict__ Cl,
                int ldc, long sC,
                const float* __restrict__ bias)
{
    constexpr int SUBM = BM / 2, SUBN = BN / 2;
    constexpr int MR = SUBM / 16, NR = SUBN / 16;
    __shared__ u16 LA_h[BM * 32];
    __shared__ u16 LA_l[BM * 32];
    __shared__ u16 LB_h[BN * 32];
    __shared__ u16 LB_l[BN * 32];

    const int tid = threadIdx.x;
    const int lane = tid & 63;
    const int wave = tid >> 6;
    const int wr = wave >> 1, wc = wave & 1;
    const int fr = lane & 15, kg = lane >> 4;

    const int bz = blockIdx.z;
    Ah += bz * sA; Al += bz * sA;
    Bh += bz * sB; Bl += bz * sB;
    const long cb = (long)bz * sC;

    const int m0 = blockIdx.y * BM, n0 = blockIdx.x * BN;

    f32x4 acc[MR][NR];
    #pragma unroll
    for (int i = 0; i < MR; ++i)
        #pragma unroll
        for (int j = 0; j < NR; ++j)
            acc[i][j] = (f32x4){0.f, 0.f, 0.f, 0.f};

    for (int k0 = 0; k0 < K; k0 += 32) {
        #pragma unroll
        for (int c0 = 0; c0 < BM * 4; c0 += 256) {
            int c = c0 + tid;
            long so = (long)(m0 + (c >> 2)) * lda + k0 + (c & 3) * 8;
            gload16(Ah + so, &LA_h[c * 8]);
            gload16(Al + so, &LA_l[c * 8]);
        }
        #pragma unroll
        for (int c0 = 0; c0 < BN * 4; c0 += 256) {
            int c = c0 + tid;
            long so = (long)(n0 + (c >> 2)) * ldb + k0 + (c & 3) * 8;
            gload16(Bh + so, &LB_h[c * 8]);
            gload16(Bl + so, &LB_l[c * 8]);
        }
        __syncthreads();

        short8 ah[MR], al[MR], bh[NR], bl[NR];
        #pragma unroll
        for (int i = 0; i < MR; ++i) {
            int off = (wr * SUBM + i * 16 + fr) * 32 + kg * 8;
            ah[i] = *(const short8*)&LA_h[off];
            al[i] = *(const short8*)&LA_l[off];
        }
        #pragma unroll
        for (int j = 0; j < NR; ++j) {
            int off = (wc * SUBN + j * 16 + fr) * 32 + kg * 8;
            bh[j] = *(const short8*)&LB_h[off];
            bl[j] = *(const short8*)&LB_l[off];
        }
        #pragma unroll
        for (int i = 0; i < MR; ++i)
            #pragma unroll
            for (int j = 0; j < NR; ++j) {
                acc[i][j] = __builtin_amdgcn_mfma_f32_16x16x32_bf16(ah[i], bh[j], acc[i][j], 0, 0, 0);
                acc[i][j] = __builtin_amdgcn_mfma_f32_16x16x32_bf16(ah[i], bl[j], acc[i][j], 0, 0, 0);
                acc[i][j] = __builtin_amdgcn_mfma_f32_16x16x32_bf16(al[i], bh[j], acc[i][j], 0, 0, 0);
            }
        __syncthreads();
    }

    #pragma unroll
    for (int i = 0; i < MR; ++i)
        #pragma unroll
        for (int j = 0; j < NR; ++j)
            #pragma unroll
            for (int r = 0; r < 4; ++r) {
                int row = m0 + wr * SUBM + i * 16 + kg * 4 + r;
                int col = n0 + wc * SUBN + j * 16 + fr;
                float v = acc[i][j][r];
                long o = cb + (long)row * ldc + col;
                if constexpr (EP == EP_DIST16) {
                    v = -(v * v) * (1.0f / 1024.0f);
                    u16 h, l; splt(v, h, l);
                    Ch[o] = h; Cl[o] = l;
                } else if constexpr (EP == EP_PART) {
                    Cf[o] = v;
                } else {
                    Cf[o] = v + bias[col];
                }
            }
}

// softmax over 2048 keys; in/out = hi/lo bf16 pairs, row stride 4096 u16
__global__ __launch_bounds__(256)
void softmax16(u16* __restrict__ S)
{
    long row = blockIdx.x;
    u16* hi = S + row * 4096;
    u16* lo = hi + 2048;
    int tid = threadIdx.x;
    int lane = tid & 63, w = tid >> 6;

    u16x4 h0 = ((u16x4*)hi)[tid * 2];
    u16x4 h1 = ((u16x4*)hi)[tid * 2 + 1];
    u16x4 l0 = ((u16x4*)lo)[tid * 2];
    u16x4 l1 = ((u16x4*)lo)[tid * 2 + 1];

    float v[8];
    #pragma unroll
    for (int i = 0; i < 4; ++i) {
        v[i]     = bf2f(h0[i]) + bf2f(l0[i]);
        v[4 + i] = bf2f(h1[i]) + bf2f(l1[i]);
    }

    float m = v[0];
    #pragma unroll
    for (int i = 1; i < 8; ++i) m = fmaxf(m, v[i]);
    #pragma unroll
    for (int o = 32; o; o >>= 1) m = fmaxf(m, __shfl_xor(m, o));

    __shared__ float redm[4];
    __shared__ float reds[4];
    if (lane == 0) redm[w] = m;
    __syncthreads();
    m = fmaxf(fmaxf(redm[0], redm[1]), fmaxf(redm[2], redm[3]));

    float s = 0.f;
    #pragma unroll
    for (int i = 0; i < 8; ++i) { v[i] = expf(v[i] - m); s += v[i]; }
    #pragma unroll
    for (int o = 32; o; o >>= 1) s += __shfl_xor(s, o);
    if (lane == 0) reds[w] = s;
    __syncthreads();
    s = reds[0] + reds[1] + reds[2] + reds[3];
    float inv = 1.0f / s;

    u16 h, l;
    #pragma unroll
    for (int i = 0; i < 4; ++i) {
        splt(v[i] * inv, h, l);     h0[i] = h; l0[i] = l;
        splt(v[4 + i] * inv, h, l); h1[i] = h; l1[i] = l;
    }
    ((u16x4*)hi)[tid * 2] = h0;
    ((u16x4*)hi)[tid * 2 + 1] = h1;
    ((u16x4*)lo)[tid * 2] = l0;
    ((u16x4*)lo)[tid * 2 + 1] = l1;
}

// vs hi/lo [4096,512] (2 batches of 2048) -> vsT hi/lo [2][512][2048]
__global__ __launch_bounds__(256)
void transpose16(const u16* __restrict__ vH, const u16* __restrict__ vL,
                 u16* __restrict__ tH, u16* __restrict__ tL)
{
    __shared__ float t[32][33];
    int b = blockIdx.z;
    int c0 = blockIdx.x * 32;   // over 512 cols
    int r0 = blockIdx.y * 32;   // over 2048 rows within batch
    int tx = threadIdx.x, ty = threadIdx.y;
    #pragma unroll
    for (int k = 0; k < 4; ++k) {
        long idx = (long)(b * 2048 + r0 + ty + 8 * k) * 512 + c0 + tx;
        t[ty + 8 * k][tx] = bf2f(vH[idx]) + bf2f(vL[idx]);
    }
    __syncthreads();
    long ob = (long)b * 512 * 2048;
    #pragma unroll
    for (int k = 0; k < 4; ++k) {
        float v = t[tx][ty + 8 * k];
        u16 h, l; splt(v, h, l);
        long o = ob + (long)(c0 + ty + 8 * k) * 2048 + r0 + tx;
        tH[o] = h; tL[o] = l;
    }
}

__global__ __launch_bounds__(256)
void split_arr(const float* __restrict__ in, u16* __restrict__ hi, u16* __restrict__ lo, int n4)
{
    int i = blockIdx.x * 256 + threadIdx.x;
    if (i >= n4) return;
    float4 v = ((const float4*)in)[i];
    u16x4 h4, l4;
    u16 h, l;
    splt(v.x, h, l); h4.x = h; l4.x = l;
    splt(v.y, h, l); h4.y = h; l4.y = l;
    splt(v.z, h, l); h4.z = h; l4.z = l;
    splt(v.w, h, l); h4.w = h; l4.w = l;
    ((u16x4*)hi)[i] = h4;
    ((u16x4*)lo)[i] = l4;
}

// ct = split(p0 + p1); p0 contiguous [2,2048,512]; p1 batches strided by p1bs floats
__global__ __launch_bounds__(256)
void reduce_ctx(const float* __restrict__ p0, const float* __restrict__ p1, long p1bs,
                u16* __restrict__ ctH, u16* __restrict__ ctL)
{
    int i4 = blockIdx.x * 256 + threadIdx.x;   // 524288 total
    long e = (long)i4 * 4;
    int b = (int)(e >> 20);
    long r = e & 1048575;
    float4 a = ((const float4*)p0)[i4];
    float4 c = *(const float4*)(p1 + (long)b * p1bs + r);
    u16x4 h4, l4;
    u16 h, l;
    splt(a.x + c.x, h, l); h4.x = h; l4.x = l;
    splt(a.y + c.y, h, l); h4.y = h; l4.y = l;
    splt(a.z + c.z, h, l); h4.z = h; l4.z = l;
    splt(a.w + c.w, h, l); h4.w = h; l4.w = l;
    ((u16x4*)ctH)[i4] = h4;
    ((u16x4*)ctL)[i4] = l4;
}

extern "C" void kernel_launch(void* const* d_in, const int* in_sizes, int n_in,
                              void* d_out, int out_size, void* d_ws, size_t ws_size,
                              hipStream_t stream)
{
    const float* KEY   = (const float*)d_in[0];
    const float* VALUE = (const float*)d_in[1];
    const float* QUERY = (const float*)d_in[2];
    const float* Wp[7] = {(const float*)d_in[3], (const float*)d_in[5], (const float*)d_in[7],
                          (const float*)d_in[9], (const float*)d_in[11], (const float*)d_in[13],
                          (const float*)d_in[15]};
    const float* W1b = (const float*)d_in[4];
    const float* W2b = (const float*)d_in[6];
    const float* W3b = (const float*)d_in[8];
    const float* V1b = (const float*)d_in[10];
    const float* V2b = (const float*)d_in[12];
    const float* V3b = (const float*)d_in[14];
    const float* Wob = (const float*)d_in[16];
    float* out = (float*)d_out;

    const long SEC = 4096L * 512;          // u16 elems per [4096,512] section
    const long FULL = 3 * SEC;             // 12288x512

    // ---- workspace layout (total 82,837,504 B, same as proven R3) ----
    u16* p = (u16*)d_ws;
    u16 *wH[7], *wL[7];
    for (int i = 0; i < 7; ++i) { wH[i] = p; p += 512 * 512; wL[i] = p; p += 512 * 512; }
    u16* h1H = p;            p += FULL;    // region A (L1 out, L3 out, later ct/p1)
    u16* h1L = p;            p += FULL;
    u16* BC  = p;                          // 25,165,824 u16 region B+C
    u16* cH  = BC;                         // split inputs (L1 A-operand)
    u16* cL  = BC + FULL;
    u16* h2H = BC + 2 * FULL;              // L2 out
    u16* h2L = BC + 3 * FULL;
    // post-L3 aliases inside BC:
    u16* sTu = BC;                               // scores hi/lo [2][2048][4096u16] = 33.55MB
    u16* vtH = BC + 16777216;                    // vsT hi [2][512][2048]
    u16* vtL = vtH + 2097152;
    float* p0 = (float*)(BC + 20971520);         // partial slice0 [2,2048,512] f32
    // aliases inside region A (dead parts):
    float* p1 = (float*)(h1H + 2 * SEC);         // partial slice1 batch0 (vs region)
    const long P1BS = 3145728;                   // batch stride in floats (h1 half-size)
    u16* ctH = h1H;                              // ctx hi [4096,512]
    u16* ctL = h1H + SEC;

    dim3 blk(256);

    // split weights
    for (int i = 0; i < 7; ++i)
        split_arr<<<256, blk, 0, stream>>>(Wp[i], wH[i], wL[i], 512 * 512 / 4);
    // split inputs into stacked [12288,512]
    split_arr<<<2048, blk, 0, stream>>>(KEY,   cH,           cL,           (int)(SEC / 4));
    split_arr<<<2048, blk, 0, stream>>>(QUERY, cH + SEC,     cL + SEC,     (int)(SEC / 4));
    split_arr<<<2048, blk, 0, stream>>>(VALUE, cH + 2 * SEC, cL + 2 * SEC, (int)(SEC / 4));

    // ---- merged MLP: 3 layers over 12288 rows ----
    dim3 gL(8, 96, 1);
    gemm_mlp<EP_RELU><<<gL, blk, 0, stream>>>(
        cH, cL, wH[0], wL[0], wH[3], wL[3], W1b, V1b,
        nullptr, nullptr, nullptr, h1H, h1L);
    gemm_mlp<EP_RELU><<<gL, blk, 0, stream>>>(
        h1H, h1L, wH[1], wL[1], wH[4], wL[4], W2b, V2b,
        nullptr, nullptr, nullptr, h2H, h2L);
    gemm_mlp<EP_MUL><<<gL, blk, 0, stream>>>(
        h2H, h2L, wH[2], wL[2], wH[5], wL[5], W3b, V3b,
        KEY, QUERY, VALUE, h1H, h1L);
    // h1 now holds: ks rows 0-4095, qs rows 4096-8191, vs rows 8192-12287

    // vs -> vsT hi/lo
    transpose16<<<dim3(16, 64, 2), dim3(32, 8), 0, stream>>>(
        h1H + 2 * SEC, h1L + 2 * SEC, vtH, vtL);

    // dist: sT[b,q,key] hi/lo
    gemm_split<128, 128, EP_DIST16><<<dim3(16, 16, 2), blk, 0, stream>>>(
        2048, 2048, 512,
        h1H + SEC, h1L + SEC, 512, 2048L * 512,     // qs
        h1H, h1L, 512, 2048L * 512,                 // ks
        nullptr, sTu, sTu + 2048, 4096, 2048L * 4096, nullptr);

    // softmax over keys (hi/lo in place)
    softmax16<<<dim3(4096), blk, 0, stream>>>(sTu);

    // context split-K=2: two slices of 1024 keys
    gemm_split<128, 64, EP_PART><<<dim3(8, 16, 2), blk, 0, stream>>>(
        2048, 512, 1024,
        sTu, sTu + 2048, 4096, 2048L * 4096,
        vtH, vtL, 2048, 512L * 2048,
        p0, nullptr, nullptr, 512, 1048576, nullptr);
    gemm_split<128, 64, EP_PART><<<dim3(8, 16, 2), blk, 0, stream>>>(
        2048, 512, 1024,
        sTu + 1024, sTu + 1024 + 2048, 4096, 2048L * 4096,
        vtH + 1024, vtL + 1024, 2048, 512L * 2048,
        p1, nullptr, nullptr, 512, P1BS, nullptr);

    // ct = split(p0 + p1)
    reduce_ctx<<<2048, blk, 0, stream>>>(p0, p1, P1BS, ctH, ctL);

    // output projection
    gemm_split<128, 64, EP_BIASF><<<dim3(8, 32, 1), blk, 0, stream>>>(
        4096, 512, 512, ctH, ctL, 512, 0, wH[6], wL[6], 512, 0,
        out, nullptr, nullptr, 512, 0, Wob);
}

// Round 5
// 275.816 us; speedup vs baseline: 2.4498x; 1.1092x over previous
//
#include <hip/hip_runtime.h>
#include <math.h>

typedef unsigned short u16;
typedef unsigned int u32;
typedef __attribute__((ext_vector_type(8))) short short8;
typedef __attribute__((ext_vector_type(4))) float f32x4;
typedef __attribute__((ext_vector_type(4))) u16 u16x4;

__device__ __forceinline__ void gload16(const void* g, void* l) {
    __builtin_amdgcn_global_load_lds(
        (__attribute__((address_space(1))) u32*)g,
        (__attribute__((address_space(3))) u32*)l, 16, 0, 0);
}

__device__ __forceinline__ u16 f2bf_rne(float v) {
    u32 u = __builtin_bit_cast(u32, v);
    return (u16)((u + 0x7FFFu + ((u >> 16) & 1u)) >> 16);
}
__device__ __forceinline__ float bf2f(u16 h) {
    u32 u = ((u32)h) << 16;
    return __builtin_bit_cast(float, u);
}
__device__ __forceinline__ void splt(float v, u16& h, u16& l) {
    h = f2bf_rne(v);
    l = f2bf_rne(v - bf2f(h));
}

enum { EP_RELU, EP_MUL };            // mlp_pf epilogues
enum { EP_DIST16, EP_PART };         // gemm_pf epilogues

// ================= merged MLP GEMM with 2-phase prefetch =================
// A [12288,512] hi/lo; sections of 4096 rows: 0=KEY,1=QUERY (shared W), 2=VALUE
template<int EP>
__global__ __launch_bounds__(256)
void mlp_pf(const u16* __restrict__ Ah, const u16* __restrict__ Al,
            const u16* __restrict__ BHkq, const u16* __restrict__ BLkq,
            const u16* __restrict__ BHv, const u16* __restrict__ BLv,
            const float* __restrict__ bias_kq, const float* __restrict__ bias_v,
            const float* __restrict__ Xk, const float* __restrict__ Xq,
            const float* __restrict__ Xv,
            u16* __restrict__ Ch, u16* __restrict__ Cl)
{
    __shared__ u16 LAh[2][128 * 32];
    __shared__ u16 LAl[2][128 * 32];
    __shared__ u16 LBh[2][64 * 32];
    __shared__ u16 LBl[2][64 * 32];

    const int tid = threadIdx.x;
    const int lane = tid & 63;
    const int wave = tid >> 6;
    const int wr = wave >> 1, wc = wave & 1;
    const int fr = lane & 15, kg = lane >> 4;

    const int m0 = blockIdx.y * 128, n0 = blockIdx.x * 64;
    const int sec = blockIdx.y >> 5;
    const u16* Bh = (sec == 2) ? BHv : BHkq;
    const u16* Bl = (sec == 2) ? BLv : BLkq;
    const float* bias = (sec == 2) ? bias_v : bias_kq;

    f32x4 acc[4][2];
    #pragma unroll
    for (int i = 0; i < 4; ++i)
        #pragma unroll
        for (int j = 0; j < 2; ++j)
            acc[i][j] = (f32x4){0.f, 0.f, 0.f, 0.f};

    auto STAGE = [&](int buf, int kk) {
        #pragma unroll
        for (int h = 0; h < 2; ++h) {
            int c = h * 256 + tid;
            long so = (long)(m0 + (c >> 2)) * 512 + kk + (c & 3) * 8;
            gload16(Ah + so, &LAh[buf][c * 8]);
        }
        #pragma unroll
        for (int h = 0; h < 2; ++h) {
            int c = h * 256 + tid;
            long so = (long)(m0 + (c >> 2)) * 512 + kk + (c & 3) * 8;
            gload16(Al + so, &LAl[buf][c * 8]);
        }
        {
            int c = tid;
            long so = (long)(n0 + (c >> 2)) * 512 + kk + (c & 3) * 8;
            gload16(Bh + so, &LBh[buf][c * 8]);
            gload16(Bl + so, &LBl[buf][c * 8]);
        }
    };

    auto COMPUTE = [&](int buf) {
        short8 ah[4], al[4], bh[2], bl[2];
        #pragma unroll
        for (int i = 0; i < 4; ++i) {
            int off = (wr * 64 + i * 16 + fr) * 32 + kg * 8;
            ah[i] = *(const short8*)&LAh[buf][off];
            al[i] = *(const short8*)&LAl[buf][off];
        }
        #pragma unroll
        for (int j = 0; j < 2; ++j) {
            int off = (wc * 32 + j * 16 + fr) * 32 + kg * 8;
            bh[j] = *(const short8*)&LBh[buf][off];
            bl[j] = *(const short8*)&LBl[buf][off];
        }
        #pragma unroll
        for (int i = 0; i < 4; ++i)
            #pragma unroll
            for (int j = 0; j < 2; ++j) {
                acc[i][j] = __builtin_amdgcn_mfma_f32_16x16x32_bf16(ah[i], bh[j], acc[i][j], 0, 0, 0);
                acc[i][j] = __builtin_amdgcn_mfma_f32_16x16x32_bf16(ah[i], bl[j], acc[i][j], 0, 0, 0);
                acc[i][j] = __builtin_amdgcn_mfma_f32_16x16x32_bf16(al[i], bh[j], acc[i][j], 0, 0, 0);
            }
    };

    STAGE(0, 0);
    int cur = 0;
    for (int t = 0; t < 15; ++t) {
        STAGE(cur ^ 1, (t + 1) << 5);
        asm volatile("s_waitcnt vmcnt(6)" ::: "memory");
        __builtin_amdgcn_s_barrier();
        COMPUTE(cur);
        __builtin_amdgcn_s_barrier();
        cur ^= 1;
    }
    asm volatile("s_waitcnt vmcnt(0)" ::: "memory");
    __builtin_amdgcn_s_barrier();
    COMPUTE(cur);

    const float* X = (EP == EP_MUL) ? ((sec == 0) ? Xk : (sec == 1) ? Xq : Xv) : nullptr;

    #pragma unroll
    for (int i = 0; i < 4; ++i)
        #pragma unroll
        for (int j = 0; j < 2; ++j)
            #pragma unroll
            for (int r = 0; r < 4; ++r) {
                int row = m0 + wr * 64 + i * 16 + kg * 4 + r;
                int col = n0 + wc * 32 + j * 16 + fr;
                float v = acc[i][j][r] + bias[col];
                if constexpr (EP == EP_RELU) {
                    v = fmaxf(v, 0.f);
                } else {
                    v *= X[(long)(row - (sec << 12)) * 512 + col];
                }
                long o = (long)row * 512 + col;
                u16 h, l; splt(v, h, l);
                Ch[o] = h; Cl[o] = l;
            }
}

// ================= generic 128x64 split GEMM, grid.z = batch*nsl + slice =================
template<int EP>
__global__ __launch_bounds__(256)
void gemm_pf(int K, int nsl, int KS,
             const u16* __restrict__ Ah, const u16* __restrict__ Al, int lda, long sA,
             const u16* __restrict__ Bh, const u16* __restrict__ Bl, int ldb, long sB,
             float* __restrict__ Cf, u16* __restrict__ Ch, u16* __restrict__ Cl,
             int ldc, long sC)
{
    __shared__ u16 LAh[2][128 * 32];
    __shared__ u16 LAl[2][128 * 32];
    __shared__ u16 LBh[2][64 * 32];
    __shared__ u16 LBl[2][64 * 32];

    const int tid = threadIdx.x;
    const int lane = tid & 63;
    const int wave = tid >> 6;
    const int wr = wave >> 1, wc = wave & 1;
    const int fr = lane & 15, kg = lane >> 4;

    const int z = blockIdx.z;
    const int b = z / nsl;
    const int s = z - b * nsl;
    const int k0 = s * KS;
    int k1 = k0 + KS; if (k1 > K) k1 = K;
    const int nt = (k1 - k0) >> 5;

    Ah += b * sA; Al += b * sA;
    Bh += b * sB; Bl += b * sB;
    const long cb = (long)z * sC;

    const int m0 = blockIdx.y * 128, n0 = blockIdx.x * 64;

    f32x4 acc[4][2];
    #pragma unroll
    for (int i = 0; i < 4; ++i)
        #pragma unroll
        for (int j = 0; j < 2; ++j)
            acc[i][j] = (f32x4){0.f, 0.f, 0.f, 0.f};

    auto STAGE = [&](int buf, int kk) {
        #pragma unroll
        for (int h = 0; h < 2; ++h) {
            int c = h * 256 + tid;
            long so = (long)(m0 + (c >> 2)) * lda + kk + (c & 3) * 8;
            gload16(Ah + so, &LAh[buf][c * 8]);
        }
        #pragma unroll
        for (int h = 0; h < 2; ++h) {
            int c = h * 256 + tid;
            long so = (long)(m0 + (c >> 2)) * lda + kk + (c & 3) * 8;
            gload16(Al + so, &LAl[buf][c * 8]);
        }
        {
            int c = tid;
            long so = (long)(n0 + (c >> 2)) * ldb + kk + (c & 3) * 8;
            gload16(Bh + so, &LBh[buf][c * 8]);
            gload16(Bl + so, &LBl[buf][c * 8]);
        }
    };

    auto COMPUTE = [&](int buf) {
        short8 ah[4], al[4], bh[2], bl[2];
        #pragma unroll
        for (int i = 0; i < 4; ++i) {
            int off = (wr * 64 + i * 16 + fr) * 32 + kg * 8;
            ah[i] = *(const short8*)&LAh[buf][off];
            al[i] = *(const short8*)&LAl[buf][off];
        }
        #pragma unroll
        for (int j = 0; j < 2; ++j) {
            int off = (wc * 32 + j * 16 + fr) * 32 + kg * 8;
            bh[j] = *(const short8*)&LBh[buf][off];
            bl[j] = *(const short8*)&LBl[buf][off];
        }
        #pragma unroll
        for (int i = 0; i < 4; ++i)
            #pragma unroll
            for (int j = 0; j < 2; ++j) {
                acc[i][j] = __builtin_amdgcn_mfma_f32_16x16x32_bf16(ah[i], bh[j], acc[i][j], 0, 0, 0);
                acc[i][j] = __builtin_amdgcn_mfma_f32_16x16x32_bf16(ah[i], bl[j], acc[i][j], 0, 0, 0);
                acc[i][j] = __builtin_amdgcn_mfma_f32_16x16x32_bf16(al[i], bh[j], acc[i][j], 0, 0, 0);
            }
    };

    STAGE(0, k0);
    int cur = 0;
    for (int t = 0; t < nt - 1; ++t) {
        STAGE(cur ^ 1, k0 + ((t + 1) << 5));
        asm volatile("s_waitcnt vmcnt(6)" ::: "memory");
        __builtin_amdgcn_s_barrier();
        COMPUTE(cur);
        __builtin_amdgcn_s_barrier();
        cur ^= 1;
    }
    asm volatile("s_waitcnt vmcnt(0)" ::: "memory");
    __builtin_amdgcn_s_barrier();
    COMPUTE(cur);

    #pragma unroll
    for (int i = 0; i < 4; ++i)
        #pragma unroll
        for (int j = 0; j < 2; ++j)
            #pragma unroll
            for (int r = 0; r < 4; ++r) {
                int row = m0 + wr * 64 + i * 16 + kg * 4 + r;
                int col = n0 + wc * 32 + j * 16 + fr;
                float v = acc[i][j][r];
                long o = cb + (long)row * ldc + col;
                if constexpr (EP == EP_DIST16) {
                    v = -(v * v) * (1.0f / 1024.0f);
                    u16 h, l; splt(v, h, l);
                    Ch[o] = h; Cl[o] = l;
                } else {
                    Cf[o] = v;
                }
            }
}

// softmax over 2048 keys; in/out = hi/lo bf16 pairs, row stride 4096 u16
__global__ __launch_bounds__(256)
void softmax16(u16* __restrict__ S)
{
    long row = blockIdx.x;
    u16* hi = S + row * 4096;
    u16* lo = hi + 2048;
    int tid = threadIdx.x;
    int lane = tid & 63, w = tid >> 6;

    u16x4 h0 = ((u16x4*)hi)[tid * 2];
    u16x4 h1 = ((u16x4*)hi)[tid * 2 + 1];
    u16x4 l0 = ((u16x4*)lo)[tid * 2];
    u16x4 l1 = ((u16x4*)lo)[tid * 2 + 1];

    float v[8];
    #pragma unroll
    for (int i = 0; i < 4; ++i) {
        v[i]     = bf2f(h0[i]) + bf2f(l0[i]);
        v[4 + i] = bf2f(h1[i]) + bf2f(l1[i]);
    }

    float m = v[0];
    #pragma unroll
    for (int i = 1; i < 8; ++i) m = fmaxf(m, v[i]);
    #pragma unroll
    for (int o = 32; o; o >>= 1) m = fmaxf(m, __shfl_xor(m, o));

    __shared__ float redm[4];
    __shared__ float reds[4];
    if (lane == 0) redm[w] = m;
    __syncthreads();
    m = fmaxf(fmaxf(redm[0], redm[1]), fmaxf(redm[2], redm[3]));

    float s = 0.f;
    #pragma unroll
    for (int i = 0; i < 8; ++i) { v[i] = expf(v[i] - m); s += v[i]; }
    #pragma unroll
    for (int o = 32; o; o >>= 1) s += __shfl_xor(s, o);
    if (lane == 0) reds[w] = s;
    __syncthreads();
    s = reds[0] + reds[1] + reds[2] + reds[3];
    float inv = 1.0f / s;

    u16 h, l;
    #pragma unroll
    for (int i = 0; i < 4; ++i) {
        splt(v[i] * inv, h, l);     h0[i] = h; l0[i] = l;
        splt(v[4 + i] * inv, h, l); h1[i] = h; l1[i] = l;
    }
    ((u16x4*)hi)[tid * 2] = h0;
    ((u16x4*)hi)[tid * 2 + 1] = h1;
    ((u16x4*)lo)[tid * 2] = l0;
    ((u16x4*)lo)[tid * 2 + 1] = l1;
}

// vs hi/lo [4096,512] (2 batches of 2048) -> vsT hi/lo [2][512][2048]
__global__ __launch_bounds__(256)
void transpose16(const u16* __restrict__ vH, const u16* __restrict__ vL,
                 u16* __restrict__ tH, u16* __restrict__ tL)
{
    __shared__ float t[32][33];
    int b = blockIdx.z;
    int c0 = blockIdx.x * 32;
    int r0 = blockIdx.y * 32;
    int tx = threadIdx.x, ty = threadIdx.y;
    #pragma unroll
    for (int k = 0; k < 4; ++k) {
        long idx = (long)(b * 2048 + r0 + ty + 8 * k) * 512 + c0 + tx;
        t[ty + 8 * k][tx] = bf2f(vH[idx]) + bf2f(vL[idx]);
    }
    __syncthreads();
    long ob = (long)b * 512 * 2048;
    #pragma unroll
    for (int k = 0; k < 4; ++k) {
        float v = t[tx][ty + 8 * k];
        u16 h, l; splt(v, h, l);
        long o = ob + (long)(c0 + ty + 8 * k) * 2048 + r0 + tx;
        tH[o] = h; tL[o] = l;
    }
}

// split 7 weights in one launch; dst layout: [wi][hi 262144 | lo 262144]
__global__ __launch_bounds__(256)
void split_w(const float* __restrict__ w0, const float* __restrict__ w1,
             const float* __restrict__ w2, const float* __restrict__ w3,
             const float* __restrict__ w4, const float* __restrict__ w5,
             const float* __restrict__ w6, u16* __restrict__ dst)
{
    int wi = blockIdx.y;
    const float* src;
    switch (wi) {
        case 0: src = w0; break; case 1: src = w1; break;
        case 2: src = w2; break; case 3: src = w3; break;
        case 4: src = w4; break; case 5: src = w5; break;
        default: src = w6; break;
    }
    u16* hi = dst + (long)wi * 524288;
    u16* lo = hi + 262144;
    int i = blockIdx.x * 256 + threadIdx.x;
    float4 v = ((const float4*)src)[i];
    u16x4 h4, l4; u16 h, l;
    splt(v.x, h, l); h4.x = h; l4.x = l;
    splt(v.y, h, l); h4.y = h; l4.y = l;
    splt(v.z, h, l); h4.z = h; l4.z = l;
    splt(v.w, h, l); h4.w = h; l4.w = l;
    ((u16x4*)hi)[i] = h4;
    ((u16x4*)lo)[i] = l4;
}

// split 3 inputs (KEY,QUERY,VALUE) into stacked [12288,512] hi/lo
__global__ __launch_bounds__(256)
void split_in(const float* __restrict__ k, const float* __restrict__ q,
              const float* __restrict__ vv, u16* __restrict__ hi, u16* __restrict__ lo)
{
    int sec = blockIdx.y;
    const float* src = (sec == 0) ? k : (sec == 1) ? q : vv;
    long base4 = (long)sec * 524288;
    int i = blockIdx.x * 256 + threadIdx.x;
    float4 v = ((const float4*)src)[i];
    u16x4 h4, l4; u16 h, l;
    splt(v.x, h, l); h4.x = h; l4.x = l;
    splt(v.y, h, l); h4.y = h; l4.y = l;
    splt(v.z, h, l); h4.z = h; l4.z = l;
    splt(v.w, h, l); h4.w = h; l4.w = l;
    ((u16x4*)(hi))[base4 + i] = h4;
    ((u16x4*)(lo))[base4 + i] = l4;
}

// ct = split(sum of 3 ctx partials); P layout [b][s][2^20] f32
__global__ __launch_bounds__(256)
void reduce_ctx(const float* __restrict__ P, u16* __restrict__ ctH, u16* __restrict__ ctL)
{
    int i4 = blockIdx.x * 256 + threadIdx.x;     // 524288 float4s
    long e = (long)i4 * 4;
    int b = (int)(e >> 20);
    long r = e & ((1L << 20) - 1);
    const float* base = P + ((long)(b * 3) << 20) + r;
    float4 v0 = *(const float4*)base;
    float4 v1 = *(const float4*)(base + (1L << 20));
    float4 v2 = *(const float4*)(base + (2L << 20));
    u16x4 h4, l4; u16 h, l;
    splt(v0.x + v1.x + v2.x, h, l); h4.x = h; l4.x = l;
    splt(v0.y + v1.y + v2.y, h, l); h4.y = h; l4.y = l;
    splt(v0.z + v1.z + v2.z, h, l); h4.z = h; l4.z = l;
    splt(v0.w + v1.w + v2.w, h, l); h4.w = h; l4.w = l;
    ((u16x4*)ctH)[i4] = h4;
    ((u16x4*)ctL)[i4] = l4;
}

// out = P0 + P1 + bias
__global__ __launch_bounds__(256)
void reduce_out(const float* __restrict__ P, const float* __restrict__ bias,
                float* __restrict__ out)
{
    int i4 = blockIdx.x * 256 + threadIdx.x;     // 524288 float4s
    long e = (long)i4 * 4;
    float4 a = ((const float4*)P)[i4];
    float4 c = ((const float4*)(P + 2097152))[i4];
    float4 bb = *(const float4*)(bias + (e & 511));
    float4 o;
    o.x = a.x + c.x + bb.x;
    o.y = a.y + c.y + bb.y;
    o.z = a.z + c.z + bb.z;
    o.w = a.w + c.w + bb.w;
    ((float4*)out)[i4] = o;
}

extern "C" void kernel_launch(void* const* d_in, const int* in_sizes, int n_in,
                              void* d_out, int out_size, void* d_ws, size_t ws_size,
                              hipStream_t stream)
{
    const float* KEY   = (const float*)d_in[0];
    const float* VALUE = (const float*)d_in[1];
    const float* QUERY = (const float*)d_in[2];
    const float* W1w = (const float*)d_in[3];
    const float* W1b = (const float*)d_in[4];
    const float* W2w = (const float*)d_in[5];
    const float* W2b = (const float*)d_in[6];
    const float* W3w = (const float*)d_in[7];
    const float* W3b = (const float*)d_in[8];
    const float* V1w = (const float*)d_in[9];
    const float* V1b = (const float*)d_in[10];
    const float* V2w = (const float*)d_in[11];
    const float* V2b = (const float*)d_in[12];
    const float* V3w = (const float*)d_in[13];
    const float* V3b = (const float*)d_in[14];
    const float* Wow = (const float*)d_in[15];
    const float* Wob = (const float*)d_in[16];
    float* out = (float*)d_out;

    const long SEC  = 4096L * 512;     // 2,097,152 u16 per section
    const long FULL = 3 * SEC;         // 6,291,456

    // ---- workspace layout (82,837,504 B total) ----
    u16* Wb = (u16*)d_ws;                        // 7 x (hi|lo) = 3,670,016 u16
    u16* cH = Wb + 3670016;                      // [12288,512] hi
    u16* cL = cH + FULL;                         // lo
    u16* R1 = cL + FULL;                         // 4*FULL u16 region
    u16* h1H = R1,            *h1L = R1 + FULL;
    u16* h2H = R1 + 2 * FULL, *h2L = R1 + 3 * FULL;
    // post-L3 aliases inside R1 (h1,h2 dead):
    u16* sTu = R1;                               // scores [2][2048][4096] u16
    u16* vtH = R1 + 16777216;                    // vsT hi [2][512][2048]
    u16* vtL = vtH + 2097152;
    u16* ctH = R1 + 20971520;                    // ctx hi [4096,512]
    u16* ctL = ctH + 2097152;
    float* Pctx = (float*)cH;                    // [2][3][2^20] f32 (c dead post-L3)
    float* Pout = (float*)cH;                    // [2][4096*512] f32 (after reduce_ctx)

    u16* wH6 = Wb + 6L * 524288;
    u16* wL6 = wH6 + 262144;

    dim3 blk(256);

    split_w<<<dim3(256, 7), blk, 0, stream>>>(W1w, W2w, W3w, V1w, V2w, V3w, Wow, Wb);
    split_in<<<dim3(2048, 3), blk, 0, stream>>>(KEY, QUERY, VALUE, cH, cL);

    // ---- merged MLP: 3 layers over 12288 rows (c -> h1 -> h2 -> c) ----
    dim3 gL(8, 96, 1);
    mlp_pf<EP_RELU><<<gL, blk, 0, stream>>>(
        cH, cL, Wb, Wb + 262144, Wb + 3 * 524288, Wb + 3 * 524288 + 262144,
        W1b, V1b, nullptr, nullptr, nullptr, h1H, h1L);
    mlp_pf<EP_RELU><<<gL, blk, 0, stream>>>(
        h1H, h1L, Wb + 524288, Wb + 524288 + 262144, Wb + 4 * 524288, Wb + 4 * 524288 + 262144,
        W2b, V2b, nullptr, nullptr, nullptr, h2H, h2L);
    mlp_pf<EP_MUL><<<gL, blk, 0, stream>>>(
        h2H, h2L, Wb + 2 * 524288, Wb + 2 * 524288 + 262144, Wb + 5 * 524288, Wb + 5 * 524288 + 262144,
        W3b, V3b, KEY, QUERY, VALUE, cH, cL);
    // c now holds: ks rows 0-4095, qs rows 4096-8191, vs rows 8192-12287

    // vs -> vsT hi/lo
    transpose16<<<dim3(16, 64, 2), dim3(32, 8), 0, stream>>>(
        cH + 2 * SEC, cL + 2 * SEC, vtH, vtL);

    // dist: sT[b,q,key] hi/lo ; grid.z = batch
    gemm_pf<EP_DIST16><<<dim3(32, 16, 2), blk, 0, stream>>>(
        512, 1, 512,
        cH + SEC, cL + SEC, 512, 1048576,     // qs
        cH, cL, 512, 1048576,                 // ks
        nullptr, sTu, sTu + 2048, 4096, 8388608);

    // softmax over keys (hi/lo in place)
    softmax16<<<dim3(4096), blk, 0, stream>>>(sTu);

    // context split-K3 in one launch: grid.z = b*3 + s
    gemm_pf<EP_PART><<<dim3(8, 16, 6), blk, 0, stream>>>(
        2048, 3, 704,
        sTu, sTu + 2048, 4096, 8388608,
        vtH, vtL, 2048, 1048576,
        Pctx, nullptr, nullptr, 512, 1048576);

    reduce_ctx<<<dim3(2048), blk, 0, stream>>>(Pctx, ctH, ctL);

    // output projection split-K2: grid.z = s
    gemm_pf<EP_PART><<<dim3(8, 32, 2), blk, 0, stream>>>(
        512, 2, 256,
        ctH, ctL, 512, 0,
        wH6, wL6, 512, 0,
        Pout, nullptr, nullptr, 512, 2097152);

    reduce_out<<<dim3(2048), blk, 0, stream>>>(Pout, Wob, out);
}

// Round 6
// 221.380 us; speedup vs baseline: 3.0522x; 1.2459x over previous
//
#include <hip/hip_runtime.h>
#include <math.h>

typedef unsigned short u16;
typedef unsigned int u32;
typedef __attribute__((ext_vector_type(8))) short short8;
typedef __attribute__((ext_vector_type(4))) float f32x4;
typedef __attribute__((ext_vector_type(4))) u16 u16x4;

__device__ __forceinline__ void gload16(const void* g, void* l) {
    __builtin_amdgcn_global_load_lds(
        (__attribute__((address_space(1))) u32*)g,
        (__attribute__((address_space(3))) u32*)l, 16, 0, 0);
}

__device__ __forceinline__ u16 f2bf_rne(float v) {
    u32 u = __builtin_bit_cast(u32, v);
    return (u16)((u + 0x7FFFu + ((u >> 16) & 1u)) >> 16);
}
__device__ __forceinline__ float bf2f(u16 h) {
    u32 u = ((u32)h) << 16;
    return __builtin_bit_cast(float, u);
}
__device__ __forceinline__ void splt(float v, u16& h, u16& l) {
    h = f2bf_rne(v);
    l = f2bf_rne(v - bf2f(h));
}

enum { EP_RELU, EP_MUL };            // mlp_pf epilogues
enum { EP_DIST16, EP_PART };         // gemm_pf epilogues
enum { RM_CHUNK, RM_DIST2D };        // XCD remap modes

// ================= merged MLP GEMM with 2-phase prefetch =================
// A [12288,512] hi/lo; sections of 4096 rows: 0=KEY,1=QUERY (shared W), 2=VALUE
// grid MUST be (8,96,1). XCD-chunked remap: panel = xcd*12 + slot.
template<int EP>
__global__ __launch_bounds__(256)
void mlp_pf(const u16* __restrict__ Ah, const u16* __restrict__ Al,
            const u16* __restrict__ BHkq, const u16* __restrict__ BLkq,
            const u16* __restrict__ BHv, const u16* __restrict__ BLv,
            const float* __restrict__ bias_kq, const float* __restrict__ bias_v,
            const float* __restrict__ Xk, const float* __restrict__ Xq,
            const float* __restrict__ Xv,
            u16* __restrict__ Ch, u16* __restrict__ Cl)
{
    __shared__ u16 LAh[2][128 * 32];
    __shared__ u16 LAl[2][128 * 32];
    __shared__ u16 LBh[2][64 * 32];
    __shared__ u16 LBl[2][64 * 32];

    const int tid = threadIdx.x;
    const int lane = tid & 63;
    const int wave = tid >> 6;
    const int wr = wave >> 1, wc = wave & 1;
    const int fr = lane & 15, kg = lane >> 4;

    // XCD-aware remap: each XCD owns 12 contiguous row-panels (L2-resident A)
    const int L = blockIdx.y * 8 + blockIdx.x;
    const int xcd = L & 7;
    const int i = L >> 3;                 // 0..95
    const int panel = xcd * 12 + (i >> 3);
    const int m0 = panel * 128, n0 = (i & 7) * 64;
    const int sec = panel >> 5;

    const u16* Bh = (sec == 2) ? BHv : BHkq;
    const u16* Bl = (sec == 2) ? BLv : BLkq;
    const float* bias = (sec == 2) ? bias_v : bias_kq;

    f32x4 acc[4][2];
    #pragma unroll
    for (int a = 0; a < 4; ++a)
        #pragma unroll
        for (int j = 0; j < 2; ++j)
            acc[a][j] = (f32x4){0.f, 0.f, 0.f, 0.f};

    auto STAGE = [&](int buf, int kk) {
        #pragma unroll
        for (int h = 0; h < 2; ++h) {
            int c = h * 256 + tid;
            long so = (long)(m0 + (c >> 2)) * 512 + kk + (c & 3) * 8;
            gload16(Ah + so, &LAh[buf][c * 8]);
        }
        #pragma unroll
        for (int h = 0; h < 2; ++h) {
            int c = h * 256 + tid;
            long so = (long)(m0 + (c >> 2)) * 512 + kk + (c & 3) * 8;
            gload16(Al + so, &LAl[buf][c * 8]);
        }
        {
            int c = tid;
            long so = (long)(n0 + (c >> 2)) * 512 + kk + (c & 3) * 8;
            gload16(Bh + so, &LBh[buf][c * 8]);
            gload16(Bl + so, &LBl[buf][c * 8]);
        }
    };

    auto COMPUTE = [&](int buf) {
        short8 ah[4], al[4], bh[2], bl[2];
        #pragma unroll
        for (int a = 0; a < 4; ++a) {
            int off = (wr * 64 + a * 16 + fr) * 32 + kg * 8;
            ah[a] = *(const short8*)&LAh[buf][off];
            al[a] = *(const short8*)&LAl[buf][off];
        }
        #pragma unroll
        for (int j = 0; j < 2; ++j) {
            int off = (wc * 32 + j * 16 + fr) * 32 + kg * 8;
            bh[j] = *(const short8*)&LBh[buf][off];
            bl[j] = *(const short8*)&LBl[buf][off];
        }
        #pragma unroll
        for (int a = 0; a < 4; ++a)
            #pragma unroll
            for (int j = 0; j < 2; ++j) {
                acc[a][j] = __builtin_amdgcn_mfma_f32_16x16x32_bf16(ah[a], bh[j], acc[a][j], 0, 0, 0);
                acc[a][j] = __builtin_amdgcn_mfma_f32_16x16x32_bf16(ah[a], bl[j], acc[a][j], 0, 0, 0);
                acc[a][j] = __builtin_amdgcn_mfma_f32_16x16x32_bf16(al[a], bh[j], acc[a][j], 0, 0, 0);
            }
    };

    STAGE(0, 0);
    int cur = 0;
    for (int t = 0; t < 15; ++t) {
        STAGE(cur ^ 1, (t + 1) << 5);
        asm volatile("s_waitcnt vmcnt(6)" ::: "memory");
        __builtin_amdgcn_s_barrier();
        COMPUTE(cur);
        __builtin_amdgcn_s_barrier();
        cur ^= 1;
    }
    asm volatile("s_waitcnt vmcnt(0)" ::: "memory");
    __builtin_amdgcn_s_barrier();
    COMPUTE(cur);

    const float* X = (EP == EP_MUL) ? ((sec == 0) ? Xk : (sec == 1) ? Xq : Xv) : nullptr;

    #pragma unroll
    for (int a = 0; a < 4; ++a)
        #pragma unroll
        for (int j = 0; j < 2; ++j)
            #pragma unroll
            for (int r = 0; r < 4; ++r) {
                int row = m0 + wr * 64 + a * 16 + kg * 4 + r;
                int col = n0 + wc * 32 + j * 16 + fr;
                float v = acc[a][j][r] + bias[col];
                if constexpr (EP == EP_RELU) {
                    v = fmaxf(v, 0.f);
                } else {
                    v *= X[(long)(row - (sec << 12)) * 512 + col];
                }
                long o = (long)row * 512 + col;
                u16 h, l; splt(v, h, l);
                Ch[o] = h; Cl[o] = l;
            }
}

// ================= generic 128x64 split GEMM with XCD remap =================
// logical grid (gx, gy, gz); z = batch*nsl + slice
template<int EP, int RM>
__global__ __launch_bounds__(256)
void gemm_pf(int K, int nsl, int KS,
             const u16* __restrict__ Ah, const u16* __restrict__ Al, int lda, long sA,
             const u16* __restrict__ Bh, const u16* __restrict__ Bl, int ldb, long sB,
             float* __restrict__ Cf, u16* __restrict__ Ch, u16* __restrict__ Cl,
             int ldc, long sC)
{
    __shared__ u16 LAh[2][128 * 32];
    __shared__ u16 LAl[2][128 * 32];
    __shared__ u16 LBh[2][64 * 32];
    __shared__ u16 LBl[2][64 * 32];

    const int tid = threadIdx.x;
    const int lane = tid & 63;
    const int wave = tid >> 6;
    const int wr = wave >> 1, wc = wave & 1;
    const int fr = lane & 15, kg = lane >> 4;

    // ---- XCD-aware block remap (bijective) ----
    int bx, by, bz;
    {
        const int gx = gridDim.x, gy = gridDim.y;
        const int L = (blockIdx.z * gy + blockIdx.y) * gx + blockIdx.x;
        const int xcd = L & 7;
        const int i = L >> 3;
        if constexpr (RM == RM_DIST2D) {
            // fixed geometry: 32 m-panels x 32 n-tiles, 16 chunks of 8x8, 2/XCD
            const int c = i >> 6, pos = i & 63;
            const int chunk = c * 8 + xcd;
            const int mp = (chunk & 3) * 8 + (pos >> 3);
            bx = (chunk >> 2) * 8 + (pos & 7);
            by = mp & 15;
            bz = mp >> 4;
        } else {
            // contiguous A-panel pinning: P = gy*gz panels, P/8 per XCD
            const int P = gy * gridDim.z;
            const int ppx = P >> 3;
            const int xt = i % gx;
            const int panel = xcd * ppx + i / gx;
            bx = xt;
            by = panel % gy;
            bz = panel / gy;
        }
    }

    const int b = bz / nsl;
    const int s = bz - b * nsl;
    const int k0 = s * KS;
    int k1 = k0 + KS; if (k1 > K) k1 = K;
    const int nt = (k1 - k0) >> 5;

    Ah += b * sA; Al += b * sA;
    Bh += b * sB; Bl += b * sB;
    const long cb = (long)bz * sC;

    const int m0 = by * 128, n0 = bx * 64;

    f32x4 acc[4][2];
    #pragma unroll
    for (int a = 0; a < 4; ++a)
        #pragma unroll
        for (int j = 0; j < 2; ++j)
            acc[a][j] = (f32x4){0.f, 0.f, 0.f, 0.f};

    auto STAGE = [&](int buf, int kk) {
        #pragma unroll
        for (int h = 0; h < 2; ++h) {
            int c = h * 256 + tid;
            long so = (long)(m0 + (c >> 2)) * lda + kk + (c & 3) * 8;
            gload16(Ah + so, &LAh[buf][c * 8]);
        }
        #pragma unroll
        for (int h = 0; h < 2; ++h) {
            int c = h * 256 + tid;
            long so = (long)(m0 + (c >> 2)) * lda + kk + (c & 3) * 8;
            gload16(Al + so, &LAl[buf][c * 8]);
        }
        {
            int c = tid;
            long so = (long)(n0 + (c >> 2)) * ldb + kk + (c & 3) * 8;
            gload16(Bh + so, &LBh[buf][c * 8]);
            gload16(Bl + so, &LBl[buf][c * 8]);
        }
    };

    auto COMPUTE = [&](int buf) {
        short8 ah[4], al[4], bh[2], bl[2];
        #pragma unroll
        for (int a = 0; a < 4; ++a) {
            int off = (wr * 64 + a * 16 + fr) * 32 + kg * 8;
            ah[a] = *(const short8*)&LAh[buf][off];
            al[a] = *(const short8*)&LAl[buf][off];
        }
        #pragma unroll
        for (int j = 0; j < 2; ++j) {
            int off = (wc * 32 + j * 16 + fr) * 32 + kg * 8;
            bh[j] = *(const short8*)&LBh[buf][off];
            bl[j] = *(const short8*)&LBl[buf][off];
        }
        #pragma unroll
        for (int a = 0; a < 4; ++a)
            #pragma unroll
            for (int j = 0; j < 2; ++j) {
                acc[a][j] = __builtin_amdgcn_mfma_f32_16x16x32_bf16(ah[a], bh[j], acc[a][j], 0, 0, 0);
                acc[a][j] = __builtin_amdgcn_mfma_f32_16x16x32_bf16(ah[a], bl[j], acc[a][j], 0, 0, 0);
                acc[a][j] = __builtin_amdgcn_mfma_f32_16x16x32_bf16(al[a], bh[j], acc[a][j], 0, 0, 0);
            }
    };

    STAGE(0, k0);
    int cur = 0;
    for (int t = 0; t < nt - 1; ++t) {
        STAGE(cur ^ 1, k0 + ((t + 1) << 5));
        asm volatile("s_waitcnt vmcnt(6)" ::: "memory");
        __builtin_amdgcn_s_barrier();
        COMPUTE(cur);
        __builtin_amdgcn_s_barrier();
        cur ^= 1;
    }
    asm volatile("s_waitcnt vmcnt(0)" ::: "memory");
    __builtin_amdgcn_s_barrier();
    COMPUTE(cur);

    #pragma unroll
    for (int a = 0; a < 4; ++a)
        #pragma unroll
        for (int j = 0; j < 2; ++j)
            #pragma unroll
            for (int r = 0; r < 4; ++r) {
                int row = m0 + wr * 64 + a * 16 + kg * 4 + r;
                int col = n0 + wc * 32 + j * 16 + fr;
                float v = acc[a][j][r];
                long o = cb + (long)row * ldc + col;
                if constexpr (EP == EP_DIST16) {
                    v = -(v * v) * (1.0f / 1024.0f);
                    u16 h, l; splt(v, h, l);
                    Ch[o] = h; Cl[o] = l;
                } else {
                    Cf[o] = v;
                }
            }
}

// softmax over 2048 keys; in/out = hi/lo bf16 pairs, row stride 4096 u16
__global__ __launch_bounds__(256)
void softmax16(u16* __restrict__ S)
{
    long row = blockIdx.x;
    u16* hi = S + row * 4096;
    u16* lo = hi + 2048;
    int tid = threadIdx.x;
    int lane = tid & 63, w = tid >> 6;

    u16x4 h0 = ((u16x4*)hi)[tid * 2];
    u16x4 h1 = ((u16x4*)hi)[tid * 2 + 1];
    u16x4 l0 = ((u16x4*)lo)[tid * 2];
    u16x4 l1 = ((u16x4*)lo)[tid * 2 + 1];

    float v[8];
    #pragma unroll
    for (int i = 0; i < 4; ++i) {
        v[i]     = bf2f(h0[i]) + bf2f(l0[i]);
        v[4 + i] = bf2f(h1[i]) + bf2f(l1[i]);
    }

    float m = v[0];
    #pragma unroll
    for (int i = 1; i < 8; ++i) m = fmaxf(m, v[i]);
    #pragma unroll
    for (int o = 32; o; o >>= 1) m = fmaxf(m, __shfl_xor(m, o));

    __shared__ float redm[4];
    __shared__ float reds[4];
    if (lane == 0) redm[w] = m;
    __syncthreads();
    m = fmaxf(fmaxf(redm[0], redm[1]), fmaxf(redm[2], redm[3]));

    float s = 0.f;
    #pragma unroll
    for (int i = 0; i < 8; ++i) { v[i] = expf(v[i] - m); s += v[i]; }
    #pragma unroll
    for (int o = 32; o; o >>= 1) s += __shfl_xor(s, o);
    if (lane == 0) reds[w] = s;
    __syncthreads();
    s = reds[0] + reds[1] + reds[2] + reds[3];
    float inv = 1.0f / s;

    u16 h, l;
    #pragma unroll
    for (int i = 0; i < 4; ++i) {
        splt(v[i] * inv, h, l);     h0[i] = h; l0[i] = l;
        splt(v[4 + i] * inv, h, l); h1[i] = h; l1[i] = l;
    }
    ((u16x4*)hi)[tid * 2] = h0;
    ((u16x4*)hi)[tid * 2 + 1] = h1;
    ((u16x4*)lo)[tid * 2] = l0;
    ((u16x4*)lo)[tid * 2 + 1] = l1;
}

// vs hi/lo [4096,512] (2 batches of 2048) -> vsT hi/lo [2][512][2048]
__global__ __launch_bounds__(256)
void transpose16(const u16* __restrict__ vH, const u16* __restrict__ vL,
                 u16* __restrict__ tH, u16* __restrict__ tL)
{
    __shared__ float t[32][33];
    int b = blockIdx.z;
    int c0 = blockIdx.x * 32;
    int r0 = blockIdx.y * 32;
    int tx = threadIdx.x, ty = threadIdx.y;
    #pragma unroll
    for (int k = 0; k < 4; ++k) {
        long idx = (long)(b * 2048 + r0 + ty + 8 * k) * 512 + c0 + tx;
        t[ty + 8 * k][tx] = bf2f(vH[idx]) + bf2f(vL[idx]);
    }
    __syncthreads();
    long ob = (long)b * 512 * 2048;
    #pragma unroll
    for (int k = 0; k < 4; ++k) {
        float v = t[tx][ty + 8 * k];
        u16 h, l; splt(v, h, l);
        long o = ob + (long)(c0 + ty + 8 * k) * 2048 + r0 + tx;
        tH[o] = h; tL[o] = l;
    }
}

// split 7 weights in one launch; dst layout: [wi][hi 262144 | lo 262144]
__global__ __launch_bounds__(256)
void split_w(const float* __restrict__ w0, const float* __restrict__ w1,
             const float* __restrict__ w2, const float* __restrict__ w3,
             const float* __restrict__ w4, const float* __restrict__ w5,
             const float* __restrict__ w6, u16* __restrict__ dst)
{
    int wi = blockIdx.y;
    const float* src;
    switch (wi) {
        case 0: src = w0; break; case 1: src = w1; break;
        case 2: src = w2; break; case 3: src = w3; break;
        case 4: src = w4; break; case 5: src = w5; break;
        default: src = w6; break;
    }
    u16* hi = dst + (long)wi * 524288;
    u16* lo = hi + 262144;
    int i = blockIdx.x * 256 + threadIdx.x;
    float4 v = ((const float4*)src)[i];
    u16x4 h4, l4; u16 h, l;
    splt(v.x, h, l); h4.x = h; l4.x = l;
    splt(v.y, h, l); h4.y = h; l4.y = l;
    splt(v.z, h, l); h4.z = h; l4.z = l;
    splt(v.w, h, l); h4.w = h; l4.w = l;
    ((u16x4*)hi)[i] = h4;
    ((u16x4*)lo)[i] = l4;
}

// split 3 inputs (KEY,QUERY,VALUE) into stacked [12288,512] hi/lo
__global__ __launch_bounds__(256)
void split_in(const float* __restrict__ k, const float* __restrict__ q,
              const float* __restrict__ vv, u16* __restrict__ hi, u16* __restrict__ lo)
{
    int sec = blockIdx.y;
    const float* src = (sec == 0) ? k : (sec == 1) ? q : vv;
    long base4 = (long)sec * 524288;
    int i = blockIdx.x * 256 + threadIdx.x;
    float4 v = ((const float4*)src)[i];
    u16x4 h4, l4; u16 h, l;
    splt(v.x, h, l); h4.x = h; l4.x = l;
    splt(v.y, h, l); h4.y = h; l4.y = l;
    splt(v.z, h, l); h4.z = h; l4.z = l;
    splt(v.w, h, l); h4.w = h; l4.w = l;
    ((u16x4*)(hi))[base4 + i] = h4;
    ((u16x4*)(lo))[base4 + i] = l4;
}

// ct = split(sum of 3 ctx partials); P layout [b][s][2^20] f32
__global__ __launch_bounds__(256)
void reduce_ctx(const float* __restrict__ P, u16* __restrict__ ctH, u16* __restrict__ ctL)
{
    int i4 = blockIdx.x * 256 + threadIdx.x;     // 524288 float4s
    long e = (long)i4 * 4;
    int b = (int)(e >> 20);
    long r = e & ((1L << 20) - 1);
    const float* base = P + ((long)(b * 3) << 20) + r;
    float4 v0 = *(const float4*)base;
    float4 v1 = *(const float4*)(base + (1L << 20));
    float4 v2 = *(const float4*)(base + (2L << 20));
    u16x4 h4, l4; u16 h, l;
    splt(v0.x + v1.x + v2.x, h, l); h4.x = h; l4.x = l;
    splt(v0.y + v1.y + v2.y, h, l); h4.y = h; l4.y = l;
    splt(v0.z + v1.z + v2.z, h, l); h4.z = h; l4.z = l;
    splt(v0.w + v1.w + v2.w, h, l); h4.w = h; l4.w = l;
    ((u16x4*)ctH)[i4] = h4;
    ((u16x4*)ctL)[i4] = l4;
}

// out = P0 + P1 + bias
__global__ __launch_bounds__(256)
void reduce_out(const float* __restrict__ P, const float* __restrict__ bias,
                float* __restrict__ out)
{
    int i4 = blockIdx.x * 256 + threadIdx.x;     // 524288 float4s
    long e = (long)i4 * 4;
    float4 a = ((const float4*)P)[i4];
    float4 c = ((const float4*)(P + 2097152))[i4];
    float4 bb = *(const float4*)(bias + (e & 511));
    float4 o;
    o.x = a.x + c.x + bb.x;
    o.y = a.y + c.y + bb.y;
    o.z = a.z + c.z + bb.z;
    o.w = a.w + c.w + bb.w;
    ((float4*)out)[i4] = o;
}

extern "C" void kernel_launch(void* const* d_in, const int* in_sizes, int n_in,
                              void* d_out, int out_size, void* d_ws, size_t ws_size,
                              hipStream_t stream)
{
    const float* KEY   = (const float*)d_in[0];
    const float* VALUE = (const float*)d_in[1];
    const float* QUERY = (const float*)d_in[2];
    const float* W1w = (const float*)d_in[3];
    const float* W1b = (const float*)d_in[4];
    const float* W2w = (const float*)d_in[5];
    const float* W2b = (const float*)d_in[6];
    const float* W3w = (const float*)d_in[7];
    const float* W3b = (const float*)d_in[8];
    const float* V1w = (const float*)d_in[9];
    const float* V1b = (const float*)d_in[10];
    const float* V2w = (const float*)d_in[11];
    const float* V2b = (const float*)d_in[12];
    const float* V3w = (const float*)d_in[13];
    const float* V3b = (const float*)d_in[14];
    const float* Wow = (const float*)d_in[15];
    const float* Wob = (const float*)d_in[16];
    float* out = (float*)d_out;

    const long SEC  = 4096L * 512;     // 2,097,152 u16 per section
    const long FULL = 3 * SEC;         // 6,291,456

    // ---- workspace layout (82,837,504 B total) ----
    u16* Wb = (u16*)d_ws;                        // 7 x (hi|lo) = 3,670,016 u16
    u16* cH = Wb + 3670016;                      // [12288,512] hi
    u16* cL = cH + FULL;                         // lo
    u16* R1 = cL + FULL;                         // 4*FULL u16 region
    u16* h1H = R1,            *h1L = R1 + FULL;
    u16* h2H = R1 + 2 * FULL, *h2L = R1 + 3 * FULL;
    // post-L3 aliases inside R1 (h1,h2 dead):
    u16* sTu = R1;                               // scores [2][2048][4096] u16
    u16* vtH = R1 + 16777216;                    // vsT hi [2][512][2048]
    u16* vtL = vtH + 2097152;
    u16* ctH = R1 + 20971520;                    // ctx hi [4096,512]
    u16* ctL = ctH + 2097152;
    float* Pctx = (float*)cH;                    // [2][3][2^20] f32 (c dead post-L3)
    float* Pout = (float*)cH;                    // [2][4096*512] f32 (after reduce_ctx)

    u16* wH6 = Wb + 6L * 524288;
    u16* wL6 = wH6 + 262144;

    dim3 blk(256);

    split_w<<<dim3(256, 7), blk, 0, stream>>>(W1w, W2w, W3w, V1w, V2w, V3w, Wow, Wb);
    split_in<<<dim3(2048, 3), blk, 0, stream>>>(KEY, QUERY, VALUE, cH, cL);

    // ---- merged MLP: 3 layers over 12288 rows (c -> h1 -> h2 -> c) ----
    dim3 gL(8, 96, 1);
    mlp_pf<EP_RELU><<<gL, blk, 0, stream>>>(
        cH, cL, Wb, Wb + 262144, Wb + 3 * 524288, Wb + 3 * 524288 + 262144,
        W1b, V1b, nullptr, nullptr, nullptr, h1H, h1L);
    mlp_pf<EP_RELU><<<gL, blk, 0, stream>>>(
        h1H, h1L, Wb + 524288, Wb + 524288 + 262144, Wb + 4 * 524288, Wb + 4 * 524288 + 262144,
        W2b, V2b, nullptr, nullptr, nullptr, h2H, h2L);
    mlp_pf<EP_MUL><<<gL, blk, 0, stream>>>(
        h2H, h2L, Wb + 2 * 524288, Wb + 2 * 524288 + 262144, Wb + 5 * 524288, Wb + 5 * 524288 + 262144,
        W3b, V3b, KEY, QUERY, VALUE, cH, cL);
    // c now holds: ks rows 0-4095, qs rows 4096-8191, vs rows 8192-12287

    // vs -> vsT hi/lo
    transpose16<<<dim3(16, 64, 2), dim3(32, 8), 0, stream>>>(
        cH + 2 * SEC, cL + 2 * SEC, vtH, vtL);

    // dist: sT[b,q,key] hi/lo ; 2D-chunked XCD remap
    gemm_pf<EP_DIST16, RM_DIST2D><<<dim3(32, 16, 2), blk, 0, stream>>>(
        512, 1, 512,
        cH + SEC, cL + SEC, 512, 1048576,     // qs
        cH, cL, 512, 1048576,                 // ks
        nullptr, sTu, sTu + 2048, 4096, 8388608);

    // softmax over keys (hi/lo in place)
    softmax16<<<dim3(4096), blk, 0, stream>>>(sTu);

    // context split-K3 in one launch: grid.z = b*3 + s
    gemm_pf<EP_PART, RM_CHUNK><<<dim3(8, 16, 6), blk, 0, stream>>>(
        2048, 3, 704,
        sTu, sTu + 2048, 4096, 8388608,
        vtH, vtL, 2048, 1048576,
        Pctx, nullptr, nullptr, 512, 1048576);

    reduce_ctx<<<dim3(2048), blk, 0, stream>>>(Pctx, ctH, ctL);

    // output projection split-K2: grid.z = s
    gemm_pf<EP_PART, RM_CHUNK><<<dim3(8, 32, 2), blk, 0, stream>>>(
        512, 2, 256,
        ctH, ctL, 512, 0,
        wH6, wL6, 512, 0,
        Pout, nullptr, nullptr, 512, 2097152);

    reduce_out<<<dim3(2048), blk, 0, stream>>>(Pout, Wob, out);
}